// Round 1
// baseline (42.746 us; speedup 1.0000x reference)
//
#include <hip/hip_runtime.h>

// gated pool: x (32,128,112,112) f32, mask (1,1,2,2) f32, K=S=2 VALID
// out (32,128,56,56) f32
// per output pixel: gate = sum(win*mask); a = sigmoid(gate);
// out = a*max(win) + (1-a)*avg(win)

#define BC    4096   // 32*128
#define H_IN  112
#define W_IN  112
#define H_OUT 56
#define W_OUT 56
#define WOP   28     // W_OUT/2: output-pixel pairs per row

__global__ __launch_bounds__(256) void gated_pool_kernel(
    const float* __restrict__ x,
    const float* __restrict__ mask,
    float* __restrict__ out,
    int npairs)
{
    // mask is tiny + uniform: hoist to registers (L1-broadcast load)
    const float m00 = mask[0];
    const float m01 = mask[1];
    const float m10 = mask[2];
    const float m11 = mask[3];

    const int stride = gridDim.x * blockDim.x;
    for (int p = blockIdx.x * blockDim.x + threadIdx.x; p < npairs; p += stride) {
        // p -> (bc, ho, wop); wop indexes a pair of adjacent output cols
        int wop = p % WOP;
        int t   = p / WOP;
        int ho  = t % H_OUT;
        int bc  = t / H_OUT;

        size_t in_base = (size_t)bc * (H_IN * W_IN) + (size_t)(2 * ho) * W_IN + 4 * wop;
        const float4 r0 = *reinterpret_cast<const float4*>(x + in_base);
        const float4 r1 = *reinterpret_cast<const float4*>(x + in_base + W_IN);

        float2 o;
        {
            float a = r0.x, b = r0.y, c = r1.x, d = r1.y;
            float gate  = m00 * a + m01 * b + m10 * c + m11 * d;
            float alpha = 1.0f / (1.0f + __expf(-gate));
            float mx    = fmaxf(fmaxf(a, b), fmaxf(c, d));
            float av    = (a + b + c + d) * 0.25f;
            o.x = alpha * mx + (1.0f - alpha) * av;
        }
        {
            float a = r0.z, b = r0.w, c = r1.z, d = r1.w;
            float gate  = m00 * a + m01 * b + m10 * c + m11 * d;
            float alpha = 1.0f / (1.0f + __expf(-gate));
            float mx    = fmaxf(fmaxf(a, b), fmaxf(c, d));
            float av    = (a + b + c + d) * 0.25f;
            o.y = alpha * mx + (1.0f - alpha) * av;
        }

        size_t out_base = (size_t)bc * (H_OUT * W_OUT) + (size_t)ho * W_OUT + 2 * wop;
        *reinterpret_cast<float2*>(out + out_base) = o;
    }
}

extern "C" void kernel_launch(void* const* d_in, const int* in_sizes, int n_in,
                              void* d_out, int out_size, void* d_ws, size_t ws_size,
                              hipStream_t stream) {
    const float* x    = (const float*)d_in[0];
    const float* mask = (const float*)d_in[1];
    float* out        = (float*)d_out;

    const int npairs = BC * H_OUT * WOP;  // 6,422,528
    const int block  = 256;
    const int grid   = 4096;              // 16 blocks/CU, grid-stride

    gated_pool_kernel<<<grid, block, 0, stream>>>(x, mask, out, npairs);
}